// Round 5
// baseline (224.004 us; speedup 1.0000x reference)
//
#include <hip/hip_runtime.h>

// GaussianActionField: out[b][k][y] = sum_n exp(-(x[b]·P[n,:,k] - pos[n]·P[n,:,k])^2 / (2 sigma[n,k]^2)) * color[n][y]
// B=256 N=65536 XD=32 YD=64 K=8. sigma=0.01 -> ~0.74% of (b,n,k) survive exp underflow.
// gaf_screen: one block per 16-n chunk, all 256 b. bf16 MFMA computes S=x·P;
//   |S-posP| < 7.4466*sigma+0.09 -> ballot-compacted LDS worklist -> exact fp32
//   recompute (x + P gathered from global, L2-hot) -> (n,g) into per-(b,k) buckets.
// gaf_phase2: one 4-wave block per (b,k) bucket reduces g*color into out.

typedef __attribute__((ext_vector_type(8))) short short8;
typedef __attribute__((ext_vector_type(4))) float f32x4;

#define NTOT   65536
#define XD     32
#define YD     64
#define KK     8
#define BB     256
#define CN     16        // n's per chunk/block
#define NKC    (CN*KK)   // 128 nk columns per chunk
#define TPB1   256       // 4 waves; ~17KB LDS -> 8 blocks/CU
#define WLCAP  1280      // expected ~512 entries/block, sigma~44 -> 17-sigma margin
#define PBS    40        // sPb stride (bf16 elems): 80B rows
#define NTILES (BB*KK)

__device__ __forceinline__ unsigned short f2bf(float f) {   // fp32 -> bf16 RNE
  unsigned u = __float_as_uint(f);
  u += 0x7FFFu + ((u >> 16) & 1u);
  return (unsigned short)(u >> 16);
}

__global__ __launch_bounds__(TPB1, 8)
void gaf_screen(const float* __restrict__ x, const float* __restrict__ pos,
                const float* __restrict__ proj, const float* __restrict__ sig,
                unsigned* __restrict__ cnt, int2* __restrict__ ent, int cap) {
  __shared__ unsigned short sPb[NKC][PBS];     // P bf16 [nk][i]   10240B
  __shared__ float2         sMeta[NKC];        // (posP, csq)       1024B
  __shared__ float          sInv[NKC];         // -log2e/(2 s^2)     512B
  __shared__ unsigned       sWl[WLCAP];        //                   5120B
  __shared__ unsigned       sWcnt;

  const int t  = threadIdx.x;
  const int n0 = blockIdx.x * CN;
  if (t == 0) sWcnt = 0u;

  // ---- stage P chunk as bf16 (1024 float4, coalesced) ----
  {
    const float4* Pg = (const float4*)(proj + (size_t)n0 * XD * KK);
#pragma unroll
    for (int r = 0; r < 4; ++r) {
      int f = t + r * TPB1;
      float4 v = Pg[f];
      int nn = f >> 6;                 // 64 float4 per n
      int i  = (f & 63) >> 1;          // 2 float4 per i
      int nk = nn * KK + ((f & 1) << 2);
      sPb[nk+0][i] = f2bf(v.x);  sPb[nk+1][i] = f2bf(v.y);
      sPb[nk+2][i] = f2bf(v.z);  sPb[nk+3][i] = f2bf(v.w);
    }
  }
  __syncthreads();

  // ---- exact posP (pos + P gathered from global, L2-hot), thresholds ----
  if (t < NKC) {
    int nn = t >> 3, k = t & 7;
    const float4* pg = (const float4*)(pos + (size_t)(n0 + nn) * XD);
    const float*  pk = proj + (size_t)(n0 + nn) * XD * KK + k;   // stride-8 column
    float d = 0.f;
#pragma unroll
    for (int j = 0; j < 8; ++j) {
      float4 v = pg[j];
      d = fmaf(v.x, pk[(4*j+0) * KK], d);
      d = fmaf(v.y, pk[(4*j+1) * KK], d);
      d = fmaf(v.z, pk[(4*j+2) * KK], d);
      d = fmaf(v.w, pk[(4*j+3) * KK], d);
    }
    float s = sig[(size_t)n0 * KK + t];
    float c = fmaf(7.4466f, s, 0.09f);           // exp-cut radius + bf16-error margin
    sMeta[t] = make_float2(d, c * c);
    sInv[t]  = -0.72134752044448169f / (s * s);  // -log2(e)/2 / s^2
  }
  __syncthreads();

  // ---- bf16 MFMA screen: wave w owns b-tiles w*4..w*4+3 (64 b), 8 nk-tiles ----
  const int l  = t & 63, w = t >> 6;
  const int i0 = (l >> 4) << 3;
  short8 af[4];
#pragma unroll
  for (int j = 0; j < 4; ++j) {
    const int brow = (w * 4 + j) * 16 + (l & 15);
    const float4* xr = (const float4*)(x + (size_t)brow * XD + i0);
    float4 u0 = xr[0], u1 = xr[1];
    af[j][0] = (short)f2bf(u0.x); af[j][1] = (short)f2bf(u0.y);
    af[j][2] = (short)f2bf(u0.z); af[j][3] = (short)f2bf(u0.w);
    af[j][4] = (short)f2bf(u1.x); af[j][5] = (short)f2bf(u1.y);
    af[j][6] = (short)f2bf(u1.z); af[j][7] = (short)f2bf(u1.w);
  }
  const f32x4 zero = {0.f, 0.f, 0.f, 0.f};
#pragma unroll
  for (int nkt = 0; nkt < NKC / 16; ++nkt) {
    const int col = nkt * 16 + (l & 15);
    short8 bf = *(const short8*)&sPb[col][i0];   // shared by 4 MFMAs below
    float2 mt = sMeta[col];
#pragma unroll
    for (int j = 0; j < 4; ++j) {
      f32x4 S = __builtin_amdgcn_mfma_f32_16x16x32_bf16(af[j], bf, zero, 0, 0, 0);
      unsigned rm = 0u;
#pragma unroll
      for (int r = 0; r < 4; ++r) {
        float d = S[r] - mt.x;
        if (fmaf(d, d, -mt.y) < 0.f) rm |= (1u << r);
      }
      unsigned long long msk = __ballot(rm != 0u);
      if (msk) {                                 // wave-uniform
        unsigned base = 0u;
        if (l == 0) base = atomicAdd(&sWcnt, (unsigned)__popcll(msk));
        base = __shfl(base, 0);
        if (rm) {
          unsigned off = __builtin_amdgcn_mbcnt_hi((unsigned)(msk >> 32),
                          __builtin_amdgcn_mbcnt_lo((unsigned)msk, 0u));
          unsigned idx = base + off;
          // bbase = C rows base: wave b-tile + (lane>>4)*4 ; C/D: col=lane&15, row=(l>>4)*4+r
          if (idx < WLCAP)
            sWl[idx] = (unsigned)col |
                       ((unsigned)((w * 4 + j) * 16 + ((l >> 4) << 2)) << 8) |
                       (rm << 16);
        }
      }
    }
  }
  __syncthreads();

  // ---- exact fp32 recompute of candidates -> per-(b,k) buckets ----
  int m = (int)sWcnt; if (m > WLCAP) m = WLCAP;
  for (int e = t; e < m; e += TPB1) {
    unsigned ww = sWl[e];
    int nk = (int)(ww & 255u), bb = (int)((ww >> 8) & 255u);
    unsigned rm = ww >> 16;
    int nn = nk >> 3, k = nk & 7;
    const float* pk = proj + (size_t)(n0 + nn) * XD * KK + k;   // L2-hot
    const float pp = sMeta[nk].x;
    const float ci = sInv[nk];
    while (rm) {
      int r = __ffs(rm) - 1; rm &= rm - 1u;
      int b = bb + r;
      const float4* xr = (const float4*)(x + (size_t)b * XD);
      float d0 = 0.f, d1 = 0.f;
#pragma unroll
      for (int j = 0; j < 8; ++j) {
        float4 v = xr[j];
        d0 = fmaf(v.x, pk[(4*j+0) * KK], d0);
        d1 = fmaf(v.y, pk[(4*j+1) * KK], d1);
        d0 = fmaf(v.z, pk[(4*j+2) * KK], d0);
        d1 = fmaf(v.w, pk[(4*j+3) * KK], d1);
      }
      float d  = (d0 + d1) - pp;
      float t0 = d * d * ci;
      if (t0 > -40.f) {                          // g >= 2^-40
        unsigned idx = atomicAdd(&cnt[b * KK + k], 1u);
        if (idx < (unsigned)cap)
          ent[(size_t)(b * KK + k) * cap + idx] =
              make_int2(n0 + nn, __float_as_int(__builtin_amdgcn_exp2f(t0)));
      }
    }
  }
}

__global__ __launch_bounds__(256, 8)
void gaf_phase2(const unsigned* __restrict__ cnt,
                const int2* __restrict__ ent,
                const float* __restrict__ colr,
                float* __restrict__ out,
                int cap) {
  __shared__ float sPart[4][YD];
  const int t = threadIdx.x;
  const int w = t >> 6, lane = t & 63;
  const int tile = blockIdx.x;
  int m = (int)cnt[tile];
  if (m > cap) m = cap;
  const int2* e = ent + (size_t)tile * cap;

  float a0 = 0.f, a1 = 0.f, a2 = 0.f, a3 = 0.f,
        a4 = 0.f, a5 = 0.f, a6 = 0.f, a7 = 0.f;
  int i = w;
  for (; i + 28 < m; i += 32) {                  // wave w: entries w, w+4, ..., w+28
    int2 e0 = e[i+0],  e1 = e[i+4],  e2 = e[i+8],  e3 = e[i+12];
    int2 e4 = e[i+16], e5 = e[i+20], e6 = e[i+24], e7 = e[i+28];
    a0 = fmaf(__int_as_float(e0.y), colr[(size_t)e0.x * YD + lane], a0);
    a1 = fmaf(__int_as_float(e1.y), colr[(size_t)e1.x * YD + lane], a1);
    a2 = fmaf(__int_as_float(e2.y), colr[(size_t)e2.x * YD + lane], a2);
    a3 = fmaf(__int_as_float(e3.y), colr[(size_t)e3.x * YD + lane], a3);
    a4 = fmaf(__int_as_float(e4.y), colr[(size_t)e4.x * YD + lane], a4);
    a5 = fmaf(__int_as_float(e5.y), colr[(size_t)e5.x * YD + lane], a5);
    a6 = fmaf(__int_as_float(e6.y), colr[(size_t)e6.x * YD + lane], a6);
    a7 = fmaf(__int_as_float(e7.y), colr[(size_t)e7.x * YD + lane], a7);
  }
  for (; i < m; i += 4) {
    int2 q = e[i];
    a0 = fmaf(__int_as_float(q.y), colr[(size_t)q.x * YD + lane], a0);
  }
  sPart[w][lane] = ((a0 + a1) + (a2 + a3)) + ((a4 + a5) + (a6 + a7));
  __syncthreads();
  if (w == 0)
    out[(size_t)tile * YD + lane] =
        (sPart[0][lane] + sPart[1][lane]) + (sPart[2][lane] + sPart[3][lane]);
}

extern "C" void kernel_launch(void* const* d_in, const int* in_sizes, int n_in,
                              void* d_out, int out_size, void* d_ws, size_t ws_size,
                              hipStream_t stream) {
  const float* x    = (const float*)d_in[0];
  const float* pos  = (const float*)d_in[1];
  const float* proj = (const float*)d_in[2];
  const float* colr = (const float*)d_in[3];
  const float* sig  = (const float*)d_in[4];
  float* out = (float*)d_out;

  unsigned* cnt = (unsigned*)d_ws;
  int2* ent = (int2*)((char*)d_ws + 8192);
  size_t avail = (ws_size > 8192) ? (ws_size - 8192) / (sizeof(int2) * NTILES) : 0;
  int cap = (int)(avail < 1024 ? avail : 1024);

  hipMemsetAsync(d_ws, 0, 8192, stream);         // zero bucket counters

  gaf_screen<<<NTOT / CN, TPB1, 0, stream>>>(x, pos, proj, sig, cnt, ent, cap);
  gaf_phase2<<<NTILES, 256, 0, stream>>>(cnt, ent, colr, out, cap);
}